// Round 6
// baseline (285.446 us; speedup 1.0000x reference)
//
#include <hip/hip_runtime.h>
#include <hip/hip_bf16.h>

// Problem dims
#define B_    2
#define CIN   128
#define COUT  128
#define DD    16
#define HH    32
#define WW    32
// out strides: [b][co][d2][h2][w2]
#define OS_H2 64
#define OS_D2 (64*64)
#define OS_CO (32*64*64)
#define OS_B  (COUT*OS_CO)

// padded bf16 pair-arrays: logical elems per row = 36 (interior w at 2..33)
// XE dword j = (elem 2j, elem 2j+1), XO dword j = (elem 2j+1, elem 2j+2)
#define PD_D  18
#define PD_H  34
#define RD    18                    // dwords per row
#define HWD   (PD_H*RD)             // 612 dwords per d-plane
#define CID   (PD_D*HWD)            // 11016 dwords per (b,ci)
#define CI8B  (8*CID*4)             // byte stride for +8 ci
#define ARRD  ((size_t)B_*CIN*CID)  // dwords per array
#define ARRB  ((int)(ARRD*4))       // 11,280,384 bytes
#define AFOLD_BYTES (8*32*8*64*16)  // 2 MiB

typedef __attribute__((ext_vector_type(8))) short  short8;
typedef __attribute__((ext_vector_type(4))) float  floatx4;

static __device__ __forceinline__ unsigned f2bf(float f) {
    union { __hip_bfloat16 h; unsigned short u; } cv;
    cv.h = __float2bfloat16(f);
    return (unsigned)cv.u;
}

// ---------------------------------------------------------------------------
// Kernel 1: fold weights -> per-parity 2x2x2 bf16 kernels, MFMA A order.
// (verified rounds 2-5)
// ---------------------------------------------------------------------------
__global__ __launch_bounds__(256) void fold_kernel(const float* __restrict__ Wk,
                                                   unsigned short* __restrict__ Afold) {
    const int t = blockIdx.x * 256 + threadIdx.x;
    const int p  = t >> 14;
    const int ks = (t >> 9) & 31;
    const int ct = (t >> 6) & 7;
    const int l  = t & 63;
    const int co = ct * 16 + (l & 15);
    const int ci = ks * 4 + (l >> 4);
    const int ed = (p >> 2) & 1, eh = (p >> 1) & 1, ew = p & 1;

    const float* w = Wk + (co * CIN + ci) * 27;
    float wv[27];
    #pragma unroll
    for (int i = 0; i < 27; ++i) wv[i] = w[i];

    short8 pk;
    #pragma unroll
    for (int tt = 0; tt < 8; ++tt) {
        const int td = (tt >> 2) & 1, th = (tt >> 1) & 1, tw = tt & 1;
        const int dlo = ed ? (td ? 2 : 0) : (td ? 1 : 0);
        const int dhi = ed ? (td ? 2 : 1) : (td ? 2 : 0);
        const int hlo = eh ? (th ? 2 : 0) : (th ? 1 : 0);
        const int hhi = eh ? (th ? 2 : 1) : (th ? 2 : 0);
        const int wlo = ew ? (tw ? 2 : 0) : (tw ? 1 : 0);
        const int whi = ew ? (tw ? 2 : 1) : (tw ? 2 : 0);
        float s = 0.f;
        for (int kd = dlo; kd <= dhi; ++kd)
            for (int kh = hlo; kh <= hhi; ++kh)
                for (int kw = wlo; kw <= whi; ++kw)
                    s += wv[kd * 9 + kh * 3 + kw];
        pk[tt] = (short)f2bf(s);
    }
    reinterpret_cast<short8*>(Afold)[t] = pk;
}

// ---------------------------------------------------------------------------
// Kernel 2: convert+pad x -> XE (even-phase bf16 pairs). Borders pre-zeroed.
// ---------------------------------------------------------------------------
__global__ __launch_bounds__(256) void pad_kernel(const float* __restrict__ x,
                                                  unsigned* __restrict__ xe) {
    const int idx = blockIdx.x * 256 + threadIdx.x;   // 0 .. 2,097,151
    const int w2 = idx & 15;
    const int h  = (idx >> 4) & 31;
    const int d  = (idx >> 9) & 15;
    const int ci = (idx >> 13) & 127;
    const int b  = (idx >> 20) & 1;
    const float2 v = *reinterpret_cast<const float2*>(
        x + (size_t)((b * CIN + ci) * DD + d) * (HH * WW) + h * WW + w2 * 2);
    xe[(size_t)((b * CIN + ci) * PD_D + d + 1) * HWD
       + (h + 1) * RD + (w2 + 1)] = f2bf(v.x) | (f2bf(v.y) << 16);
}

// ---------------------------------------------------------------------------
// Kernel 3: derive XO from XE:  XO[t] = (XE[t]>>16) | (XE[t+1]<<16)
// (row/plane borders in XE are zero, so cross-row reads are benign)
// ---------------------------------------------------------------------------
__global__ __launch_bounds__(256) void xo_kernel(const unsigned* __restrict__ xe,
                                                 unsigned* __restrict__ xo) {
    const size_t t = (size_t)blockIdx.x * 256 + threadIdx.x;   // < ARRD
    const unsigned e0 = xe[t];
    const unsigned e1 = (t + 1 < ARRD) ? xe[t + 1] : 0u;
    xo[t] = (e0 >> 16) | (e1 << 16);
}

// ---------------------------------------------------------------------------
// Kernel 4: per-parity implicit GEMM.  B staged by global_load_lds (size=4):
// linear LDS dst, swizzle folded into the per-lane GLOBAL source address,
// counted vmcnt (never 0 mid-loop), two raw s_barriers per chunk.
// ---------------------------------------------------------------------------
__global__ __launch_bounds__(256, 3) void upconv_mfma(
    const char* __restrict__ xps,            // XE base; XO at +ARRB
    const unsigned short* __restrict__ Afold,
    const float* __restrict__ bias,
    float* __restrict__ out)
{
    __shared__ short Bt[2][128 * 64];   // 2 x 16 KiB
    char* buf0 = reinterpret_cast<char*>(&Bt[0][0]);
    char* buf1 = reinterpret_cast<char*>(&Bt[1][0]);

    const int tid  = threadIdx.x;
    const int wave = tid >> 6;
    const int lane = tid & 63;

    const int d      = blockIdx.x >> 3;
    const int h_base = (blockIdx.x & 7) * 4;
    const int p      = blockIdx.y;
    const int b      = blockIdx.z;
    const int ed = (p >> 2) & 1, eh = (p >> 1) & 1, ew = p & 1;

    // ---- staging source addresses (chunk 0 state) ----
    // instr i covers LDS rows n = 32*wave + 2i + (lane>>5), phys dword lane&31.
    // logical dword kd = (lane&31) ^ ((i&7)<<2); cl = kd>>2 (ci), r = kd&3 (td,th)
    const int l31 = lane & 31, l5 = lane >> 5;
    const int colinc = (ew + l5) ? 1 : 0;
    const int isE    = (ew + l5) & 1;         // 1 -> XE, 0 -> XO
    const int pd0 = d + ed;
    const int ph0 = h_base + wave + eh;
    int goff[16];
    #pragma unroll
    for (int i = 0; i < 16; ++i) {
        const int kd = l31 ^ ((i & 7) << 2);
        const int cl = kd >> 2, r = kd & 3;
        const int dpad = pd0 + (r >> 1);
        const int hpad = ph0 + (r & 1);
        const int col  = i + colinc;
        const int dword = ((b * CIN + cl) * PD_D + dpad) * HWD + hpad * RD + col;
        goff[i] = dword * 4 + (isE ? 0 : ARRB);
    }
    const int wrow = wave * 32 * 128;         // byte offset of this wave's rows

    // ---- MFMA-read geometry (swizzled, conflict-free: verified r5) ----
    const int co0 = (wave >> 1) * 64;
    const int n0  = (wave & 1) * 64;
    const int ct0 = (wave >> 1) * 4;
    int raddr[2][4];
    #pragma unroll
    for (int ksl = 0; ksl < 2; ++ksl)
        #pragma unroll
        for (int nt = 0; nt < 4; ++nt) {
            const int n  = n0 + nt * 16 + (lane & 15);
            const int kb = ksl * 64 + (lane >> 4) * 16;
            raddr[ksl][nt] = n * 128 + (kb ^ (((n >> 1) & 7) << 4));
        }

    floatx4 acc[4][4];
    #pragma unroll
    for (int i = 0; i < 4; ++i)
        #pragma unroll
        for (int j = 0; j < 4; ++j)
            acc[i][j] = (floatx4){0.f, 0.f, 0.f, 0.f};

    const short8* Ap = reinterpret_cast<const short8*>(Afold);

    #define STAGE(nbufc)                                                        \
        do {                                                                    \
            _Pragma("unroll")                                                   \
            for (int i = 0; i < 16; ++i) {                                      \
                __builtin_amdgcn_global_load_lds(                               \
                    (const __attribute__((address_space(1))) void*)(xps + goff[i]), \
                    (__attribute__((address_space(3))) void*)((nbufc) + wrow + i * 256), \
                    4, 0, 0);                                                   \
                goff[i] += CI8B;                                                \
            }                                                                   \
        } while (0)

    #define BODYM(kc, bufc, nbufc, DO_STAGE, VMCNT_STR)                         \
        do {                                                                    \
            short8 a[2][4];                                                     \
            _Pragma("unroll")                                                   \
            for (int ksl = 0; ksl < 2; ++ksl)                                   \
                _Pragma("unroll")                                               \
                for (int ct = 0; ct < 4; ++ct)                                  \
                    a[ksl][ct] = Ap[(size_t)(((p) * 32 + (kc) * 2 + ksl) * 8    \
                                             + ct0 + ct) * 64 + lane];          \
            if (DO_STAGE) STAGE(nbufc);                                         \
            asm volatile(VMCNT_STR ::: "memory");                               \
            __builtin_amdgcn_sched_barrier(0);                                  \
            __builtin_amdgcn_s_barrier();                                       \
            __builtin_amdgcn_s_setprio(1);                                      \
            _Pragma("unroll")                                                   \
            for (int ksl = 0; ksl < 2; ++ksl) {                                 \
                short8 bfr[4];                                                  \
                _Pragma("unroll")                                               \
                for (int nt = 0; nt < 4; ++nt)                                  \
                    bfr[nt] = *reinterpret_cast<const short8*>(                 \
                        (bufc) + raddr[ksl][nt]);                               \
                _Pragma("unroll")                                               \
                for (int ct = 0; ct < 4; ++ct)                                  \
                    _Pragma("unroll")                                           \
                    for (int nt = 0; nt < 4; ++nt)                              \
                        acc[ct][nt] = __builtin_amdgcn_mfma_f32_16x16x32_bf16(  \
                            a[ksl][ct], bfr[nt], acc[ct][nt], 0, 0, 0);         \
            }                                                                   \
            __builtin_amdgcn_s_setprio(0);                                      \
            __builtin_amdgcn_sched_barrier(0);                                  \
            __builtin_amdgcn_s_barrier();                                       \
            __builtin_amdgcn_sched_barrier(0);                                  \
        } while (0)

    STAGE(buf0);   // prologue: tile 0
    for (int kc = 0; kc < 14; kc += 2) {
        BODYM(kc,     buf0, buf1, 1, "s_waitcnt vmcnt(24)");
        BODYM(kc + 1, buf1, buf0, 1, "s_waitcnt vmcnt(24)");
    }
    BODYM(14, buf0, buf1, 1, "s_waitcnt vmcnt(24)");
    BODYM(15, buf1, buf0, 0, "s_waitcnt vmcnt(8)");
    #undef BODYM
    #undef STAGE

    // ---- epilogue: add bias, scatter to upsampled layout ----
    float* ob = out + (size_t)b * OS_B + (size_t)(2 * d + ed) * OS_D2;
    #pragma unroll
    for (int ct = 0; ct < 4; ++ct) {
        #pragma unroll
        for (int j = 0; j < 4; ++j) {
            const int co = co0 + ct * 16 + (lane >> 4) * 4 + j;
            const float bv = bias[co];
            #pragma unroll
            for (int nt = 0; nt < 4; ++nt) {
                const int n  = n0 + nt * 16 + (lane & 15);
                const int hh = n >> 5, wl = n & 31;
                const int h2 = 2 * (h_base + hh) + eh;
                const int w2 = 2 * wl + ew;
                ob[(size_t)co * OS_CO + h2 * OS_H2 + w2] = acc[ct][nt][j] + bv;
            }
        }
    }
}

extern "C" void kernel_launch(void* const* d_in, const int* in_sizes, int n_in,
                              void* d_out, int out_size, void* d_ws, size_t ws_size,
                              hipStream_t stream) {
    const float* x    = (const float*)d_in[0];
    const float* Wk   = (const float*)d_in[1];
    const float* bias = (const float*)d_in[2];
    float* out        = (float*)d_out;

    unsigned short* Afold = (unsigned short*)d_ws;
    char* xe = (char*)d_ws + AFOLD_BYTES;
    char* xo = xe + ARRB;

    hipMemsetAsync(xe, 0, (size_t)2 * ARRB, stream);
    pad_kernel<<<8192, 256, 0, stream>>>(x, (unsigned*)xe);
    xo_kernel<<<(unsigned)(ARRD / 256), 256, 0, stream>>>((const unsigned*)xe,
                                                          (unsigned*)xo);
    fold_kernel<<<512, 256, 0, stream>>>(Wk, Afold);

    dim3 grid(DD * 8, 8, B_);   // (128, 8 parity, 2 batch)
    upconv_mfma<<<grid, 256, 0, stream>>>(xe, Afold, bias, out);
}

// Round 7
// 115.934 us; speedup vs baseline: 2.4621x; 2.4621x over previous
//
#include <hip/hip_runtime.h>
#include <hip/hip_bf16.h>

// Problem dims
#define B_    2
#define CIN   128
#define COUT  128
#define DD    16
#define HH    32
#define WW    32
// out strides: [b][co][d2][h2][w2]
#define OS_H2 64
#define OS_D2 (64*64)
#define OS_CO (32*64*64)
#define OS_B  (COUT*OS_CO)

// phase-pair bf16 arrays, dword-granular:
//   XE[j] = (e_{2j}, e_{2j+1}),  XO[j] = (e_{2j+1}, e_{2j+2})
// row = 17 dwords (col 0 = left-border slot, cols 1..16 = j 0..15 for XE);
// rows: PD_H=34 (h -1..32), planes: PD_D=18 (d -1..16)
#define PD_D   18
#define PD_H   34
#define RD     17                      // dwords per row
#define RDB    68                      // bytes per row
#define HWDW   (PD_H*RD)               // 578 dwords per d-plane
#define PLB    (HWDW*4)                // 2312 bytes per d-plane
#define CIW    (PD_D*HWDW)             // 10404 dwords per (b,ci)
#define CIB    (CIW*4)                 // 41616 bytes
#define CI8B   (8*CIB)                 // byte stride for +8 ci
#define ARRD   ((size_t)B_*CIN*CIW)    // 2,663,424 dwords per array
#define ARRB   (ARRD*4)                // 10,653,696 bytes
#define AFOLD_BYTES (8*32*8*64*16)     // 2 MiB

typedef __attribute__((ext_vector_type(8))) short        short8;
typedef __attribute__((ext_vector_type(4))) float        floatx4;
typedef __attribute__((ext_vector_type(4))) unsigned int uint4v;

static __device__ __forceinline__ unsigned f2bf(float f) {
    union { __hip_bfloat16 h; unsigned short u; } cv;
    cv.h = __float2bfloat16(f);
    return (unsigned)cv.u;
}

// ---------------------------------------------------------------------------
// Kernel 1: fold weights -> per-parity 2x2x2 bf16 kernels, MFMA A order.
// (verified rounds 2-6)
// ---------------------------------------------------------------------------
__global__ __launch_bounds__(256) void fold_kernel(const float* __restrict__ Wk,
                                                   unsigned short* __restrict__ Afold) {
    const int t = blockIdx.x * 256 + threadIdx.x;
    const int p  = t >> 14;
    const int ks = (t >> 9) & 31;
    const int ct = (t >> 6) & 7;
    const int l  = t & 63;
    const int co = ct * 16 + (l & 15);
    const int ci = ks * 4 + (l >> 4);
    const int ed = (p >> 2) & 1, eh = (p >> 1) & 1, ew = p & 1;

    const float* w = Wk + (co * CIN + ci) * 27;
    float wv[27];
    #pragma unroll
    for (int i = 0; i < 27; ++i) wv[i] = w[i];

    short8 pk;
    #pragma unroll
    for (int tt = 0; tt < 8; ++tt) {
        const int td = (tt >> 2) & 1, th = (tt >> 1) & 1, tw = tt & 1;
        const int dlo = ed ? (td ? 2 : 0) : (td ? 1 : 0);
        const int dhi = ed ? (td ? 2 : 1) : (td ? 2 : 0);
        const int hlo = eh ? (th ? 2 : 0) : (th ? 1 : 0);
        const int hhi = eh ? (th ? 2 : 1) : (th ? 2 : 0);
        const int wlo = ew ? (tw ? 2 : 0) : (tw ? 1 : 0);
        const int whi = ew ? (tw ? 2 : 1) : (tw ? 2 : 0);
        float s = 0.f;
        for (int kd = dlo; kd <= dhi; ++kd)
            for (int kh = hlo; kh <= hhi; ++kh)
                for (int kw = wlo; kw <= whi; ++kw)
                    s += wv[kd * 9 + kh * 3 + kw];
        pk[tt] = (short)f2bf(s);
    }
    reinterpret_cast<short8*>(Afold)[t] = pk;
}

// ---------------------------------------------------------------------------
// Kernel 2: convert+pad x -> XE. Interior j=0..15 at cols 1..16; borders
// (col 0, h/d pad rows) pre-zeroed by memset.
// ---------------------------------------------------------------------------
__global__ __launch_bounds__(256) void pad_kernel(const float* __restrict__ x,
                                                  unsigned* __restrict__ xe) {
    const int idx = blockIdx.x * 256 + threadIdx.x;   // 0 .. 2,097,151
    const int w2 = idx & 15;
    const int h  = (idx >> 4) & 31;
    const int d  = (idx >> 9) & 15;
    const int ci = (idx >> 13) & 127;
    const int b  = (idx >> 20) & 1;
    const float2 v = *reinterpret_cast<const float2*>(
        x + (size_t)((b * CIN + ci) * DD + d) * (HH * WW) + h * WW + w2 * 2);
    xe[(size_t)((b * CIN + ci) * PD_D + d + 1) * HWDW
       + (h + 1) * RD + (w2 + 1)] = f2bf(v.x) | (f2bf(v.y) << 16);
}

// ---------------------------------------------------------------------------
// Kernel 3: XO[t] = (XE[t]>>16) | (XE[t+1]<<16) over the whole array.
// XE col 0 is always zero, plane/row borders zero -> XO borders correct:
// XO col 0 = (0, e0); XO col 16 = (e31, 0).
// ---------------------------------------------------------------------------
__global__ __launch_bounds__(256) void xo_kernel(const unsigned* __restrict__ xe,
                                                 unsigned* __restrict__ xo) {
    const size_t t = (size_t)blockIdx.x * 256 + threadIdx.x;   // < ARRD
    const unsigned e0 = xe[t];
    const unsigned e1 = (t + 1 < ARRD) ? xe[t + 1] : 0u;
    xo[t] = (e0 >> 16) | (e1 << 16);
}

// ---------------------------------------------------------------------------
// Kernel 4: per-parity implicit GEMM (r4 pipeline, depth-1 prefetch).
//   - B staged as 16 direct dword loads/thread from XE/XO (no extract VALU)
//   - LDS swizzle key ((n>>1)&7): conflict-free writes AND reads (r5-verified)
//   - lgkmcnt-only barrier; vmcnt never drained mid-loop
// ---------------------------------------------------------------------------
__global__ __launch_bounds__(256, 3) void upconv_mfma(
    const char* __restrict__ xe_c, const char* __restrict__ xo_c,
    const unsigned short* __restrict__ Afold,
    const float* __restrict__ bias,
    float* __restrict__ out)
{
    __shared__ short Bt[2][128 * 64];   // 2 x 16 KiB
    char* buf0 = reinterpret_cast<char*>(&Bt[0][0]);
    char* buf1 = reinterpret_cast<char*>(&Bt[1][0]);

    const int tid  = threadIdx.x;
    const int wave = tid >> 6;
    const int lane = tid & 63;

    const int d      = blockIdx.x >> 3;
    const int h_base = (blockIdx.x & 7) * 4;
    const int p      = blockIdx.y;
    const int b      = blockIdx.z;
    const int ed = (p >> 2) & 1, eh = (p >> 1) & 1, ew = p & 1;

    // ---- staging geometry (chunk-invariant) ----
    const int npair = tid & 63;
    const int grp   = tid >> 6;                 // ci-pair group 0..3
    const int hl    = npair >> 4;               // 0..3
    const int s     = npair & 15;               // w-pair index
    const int n_a   = hl * 32 + 2 * s;          // even n
    const int n_b   = n_a + 1;                  // odd n
    // array/col per class (derived & border-checked in round-7 analysis):
    //   n even: arr = ew?XE:XO, col = s+ew ;  n odd: arr = ew?XO:XE, col = s+1
    const char* pa = ew ? xe_c : xo_c;
    const char* pb = ew ? xo_c : xe_c;
    const int dpad0 = d + ed;
    const int hpad0 = h_base + hl + eh;
    const long rowb = ((long)(b * CIN + grp * 2) * PD_D + dpad0) * (long)PLB
                    + (long)hpad0 * RDB;
    int offA[2], offB[2];                       // byte offsets, advance by CI8B
    offA[0] = (int)rowb + (s + ew) * 4;
    offB[0] = (int)rowb + (s + 1) * 4;
    offA[1] = offA[0] + CIB;
    offB[1] = offB[0] + CIB;

    int waddr_a[2], waddr_b[2];
    #pragma unroll
    for (int i = 0; i < 2; ++i) {
        const int cl = grp * 2 + i;
        waddr_a[i] = n_a * 128 + ((cl * 16) ^ (((n_a >> 1) & 7) << 4));
        waddr_b[i] = n_b * 128 + ((cl * 16) ^ (((n_b >> 1) & 7) << 4));
    }

    // ---- MFMA-read geometry (chunk-invariant; r5-verified conflict-free) ----
    const int co0 = (wave >> 1) * 64;
    const int n0  = (wave & 1) * 64;
    const int ct0 = (wave >> 1) * 4;
    int raddr[2][4];
    #pragma unroll
    for (int ksl = 0; ksl < 2; ++ksl)
        #pragma unroll
        for (int nt = 0; nt < 4; ++nt) {
            const int n  = n0 + nt * 16 + (lane & 15);
            const int kb = ksl * 64 + (lane >> 4) * 16;
            raddr[ksl][nt] = n * 128 + (kb ^ (((n >> 1) & 7) << 4));
        }

    floatx4 acc[4][4];
    #pragma unroll
    for (int i = 0; i < 4; ++i)
        #pragma unroll
        for (int j = 0; j < 4; ++j)
            acc[i][j] = (floatx4){0.f, 0.f, 0.f, 0.f};

    const short8* Ap = reinterpret_cast<const short8*>(Afold);

    unsigned ga[2][4], gb[2][4];   // [ci][r], r = td*2+th; offsets {0,68,2312,2380}

    #define GATHER()                                                            \
        do {                                                                    \
            _Pragma("unroll")                                                   \
            for (int i = 0; i < 2; ++i) {                                       \
                const char* ba = pa + offA[i];                                  \
                const char* bb = pb + offB[i];                                  \
                ga[i][0] = *(const unsigned*)(ba + 0);                          \
                ga[i][1] = *(const unsigned*)(ba + RDB);                        \
                ga[i][2] = *(const unsigned*)(ba + PLB);                        \
                ga[i][3] = *(const unsigned*)(ba + PLB + RDB);                  \
                gb[i][0] = *(const unsigned*)(bb + 0);                          \
                gb[i][1] = *(const unsigned*)(bb + RDB);                        \
                gb[i][2] = *(const unsigned*)(bb + PLB);                        \
                gb[i][3] = *(const unsigned*)(bb + PLB + RDB);                  \
                offA[i] += CI8B; offB[i] += CI8B;                               \
            }                                                                   \
        } while (0)

    #define BODY(kc, bufc, dofill)                                              \
        do {                                                                    \
            short8 a[2][4];                                                     \
            _Pragma("unroll")                                                   \
            for (int ksl = 0; ksl < 2; ++ksl)                                   \
                _Pragma("unroll")                                               \
                for (int ct = 0; ct < 4; ++ct)                                  \
                    a[ksl][ct] = Ap[(size_t)(((p) * 32 + (kc) * 2 + ksl) * 8    \
                                             + ct0 + ct) * 64 + lane];          \
            _Pragma("unroll")                                                   \
            for (int i = 0; i < 2; ++i) {                                       \
                *(uint4v*)(bufc + waddr_a[i]) =                                 \
                    (uint4v){ga[i][0], ga[i][1], ga[i][2], ga[i][3]};           \
                *(uint4v*)(bufc + waddr_b[i]) =                                 \
                    (uint4v){gb[i][0], gb[i][1], gb[i][2], gb[i][3]};           \
            }                                                                   \
            if (dofill) GATHER();                                               \
            asm volatile("s_waitcnt lgkmcnt(0)\n\ts_barrier" ::: "memory");     \
            __builtin_amdgcn_s_setprio(1);                                      \
            _Pragma("unroll")                                                   \
            for (int ksl = 0; ksl < 2; ++ksl) {                                 \
                short8 bfr[4];                                                  \
                _Pragma("unroll")                                               \
                for (int nt = 0; nt < 4; ++nt)                                  \
                    bfr[nt] = *reinterpret_cast<const short8*>(                 \
                        (bufc) + raddr[ksl][nt]);                               \
                _Pragma("unroll")                                               \
                for (int ct = 0; ct < 4; ++ct)                                  \
                    _Pragma("unroll")                                           \
                    for (int nt = 0; nt < 4; ++nt)                              \
                        acc[ct][nt] = __builtin_amdgcn_mfma_f32_16x16x32_bf16(  \
                            a[ksl][ct], bfr[nt], acc[ct][nt], 0, 0, 0);         \
            }                                                                   \
            __builtin_amdgcn_s_setprio(0);                                      \
        } while (0)

    GATHER();
    for (int kc = 0; kc < 16; kc += 2) {
        BODY(kc,     buf0, true);
        BODY(kc + 1, buf1, (kc + 1) != 15);
    }
    #undef BODY
    #undef GATHER

    // ---- epilogue: add bias, scatter to upsampled layout ----
    float* ob = out + (size_t)b * OS_B + (size_t)(2 * d + ed) * OS_D2;
    #pragma unroll
    for (int ct = 0; ct < 4; ++ct) {
        #pragma unroll
        for (int j = 0; j < 4; ++j) {
            const int co = co0 + ct * 16 + (lane >> 4) * 4 + j;
            const float bv = bias[co];
            #pragma unroll
            for (int nt = 0; nt < 4; ++nt) {
                const int n  = n0 + nt * 16 + (lane & 15);
                const int hh = n >> 5, wl = n & 31;
                const int h2 = 2 * (h_base + hh) + eh;
                const int w2 = 2 * wl + ew;
                ob[(size_t)co * OS_CO + h2 * OS_H2 + w2] = acc[ct][nt][j] + bv;
            }
        }
    }
}

extern "C" void kernel_launch(void* const* d_in, const int* in_sizes, int n_in,
                              void* d_out, int out_size, void* d_ws, size_t ws_size,
                              hipStream_t stream) {
    const float* x    = (const float*)d_in[0];
    const float* Wk   = (const float*)d_in[1];
    const float* bias = (const float*)d_in[2];
    float* out        = (float*)d_out;

    unsigned short* Afold = (unsigned short*)d_ws;
    char* xe = (char*)d_ws + AFOLD_BYTES;
    char* xo = xe + ARRB;

    hipMemsetAsync(xe, 0, ARRB, stream);
    pad_kernel<<<8192, 256, 0, stream>>>(x, (unsigned*)xe);
    xo_kernel<<<(unsigned)(ARRD / 256), 256, 0, stream>>>((const unsigned*)xe,
                                                          (unsigned*)xo);
    fold_kernel<<<512, 256, 0, stream>>>(Wk, Afold);

    dim3 grid(DD * 8, 8, B_);   // (128, 8 parity, 2 batch)
    upconv_mfma<<<grid, 256, 0, stream>>>(xe, xo, Afold, bias, out);
}